// Round 2
// baseline (975.544 us; speedup 1.0000x reference)
//
#include <hip/hip_runtime.h>

// ---------- types ----------
typedef __attribute__((ext_vector_type(8))) short bf16x8;   // MFMA A/B frag (8 bf16)
typedef __attribute__((ext_vector_type(4))) float f32x4;    // MFMA C/D frag

// ---------- math helpers ----------
__device__ __forceinline__ short f2bf(float f) {
  unsigned u = __float_as_uint(f);
  u += 0x7fffu + ((u >> 16) & 1u);          // round-to-nearest-even
  return (short)(u >> 16);
}
__device__ __forceinline__ float sigm(float z) {
  return __builtin_amdgcn_rcpf(1.f + __builtin_amdgcn_exp2f(-1.44269504089f * z));
}
__device__ __forceinline__ float tanh_(float z) {
  return 1.f - 2.f * __builtin_amdgcn_rcpf(1.f + __builtin_amdgcn_exp2f(2.88539008178f * z));
}

// ---------- geometry ----------
// ws per component: 4 mats in FRAGMENT ORDER (bf16, 32768 B each) + 384 f32 biases.
// Fragment order: frag fi = (ct*4+kc)*64 + lane, 16 B each; contents j=0..7:
//   W[32*kc + 8*(lane>>4) + j (+rowoff)][16*ct + (lane&15)]
// Main-kernel read: base + (ct*4+kc)*1024 + lane*16  -> sequential, conflict-free.
#define WS_MAT_SH 16384           // shorts per matrix
#define WS_BIAS_OFF 131072        // byte offset of biases in comp block
#define WS_COMP 133120            // bytes per comp block (132608 rounded up)
#define KPS 136                   // out-staging row stride (shorts); 272 B, 16B-aligned
#define STG_B (16 * KPS * 2)      // 4352 B per wave
#define NODE_BLOCKS 391
#define EDGE_BLOCKS 782
#define GLOB_BLOCKS 4
#define NBLOCKS (NODE_BLOCKS + EDGE_BLOCKS + GLOB_BLOCKS)   // 1177

// prep: one component per launch; block m packs matrix m; block 0 also biases.
__global__ __launch_bounds__(256) void prep_weights(
    const float* __restrict__ W1, const float* __restrict__ b1,
    const float* __restrict__ W2, const float* __restrict__ b2,
    const float* __restrict__ W3, const float* __restrict__ b3,
    unsigned char* __restrict__ wsc) {
  const int m = blockIdx.x;  // 0=W1a 1=W1b 2=W2 3=W3
  short* dst = (short*)wsc + m * WS_MAT_SH;
  const float* src;
  int rowoff = 0;
  if (m == 0)      { src = W1; rowoff = 0; }
  else if (m == 1) { src = W1; rowoff = 128; }
  else if (m == 2) { src = W2; }
  else             { src = W3; }
  for (int fi = threadIdx.x; fi < 2048; fi += 256) {
    int ct = fi >> 8, kc = (fi >> 6) & 3, l = fi & 63;
    int c = l & 15, g = l >> 4;
    int col = 16 * ct + c;
    int kbase = 32 * kc + 8 * g + rowoff;
    bf16x8 v;
#pragma unroll
    for (int j = 0; j < 8; ++j) v[j] = f2bf(src[(size_t)(kbase + j) * 128 + col]);
    *(bf16x8*)(dst + fi * 8) = v;
  }
  if (m == 0) {
    float* bd = (float*)(wsc + WS_BIAS_OFF);
    for (int i = threadIdx.x; i < 384; i += 256) {
      float v = (i < 128) ? b1[i] : (i < 256) ? b2[i - 128] : b3[i - 256];
      bd[i] = v;
    }
  }
}

// main fused recurrent kernel: 4 waves/block, 32 rows/wave (2 x 16-row tiles)
__global__ __launch_bounds__(256, 1) void glstm(
    const float* __restrict__ xs, const float* __restrict__ es,
    const float* __restrict__ gs, const unsigned char* __restrict__ ws,
    float* __restrict__ dout) {
  __shared__ __align__(16) unsigned char smem[131072 + 4 * STG_B];  // 148480 B

  const int bid = blockIdx.x, tid = threadIdx.x;
  const float* X; float* S; float* O; int M; int unit, comp;
  if (bid < NODE_BLOCKS) {
    X = xs; M = 50000;  S = dout;             O = dout + 19265536L; unit = bid; comp = 0;
  } else if (bid < NODE_BLOCKS + EDGE_BLOCKS) {
    X = es; M = 100000; S = dout + 6400000L;  O = dout + 25665536L; unit = bid - NODE_BLOCKS; comp = 1;
  } else {
    X = gs; M = 512;    S = dout + 19200000L; O = dout + 38465536L; unit = bid - (NODE_BLOCKS + EDGE_BLOCKS); comp = 2;
  }

  const unsigned char* wsc = ws + (size_t)comp * WS_COMP;
  {
    const uint4* src = (const uint4*)wsc;
    uint4* dst = (uint4*)smem;
#pragma unroll 8
    for (int i = tid; i < 8192; i += 256) dst[i] = src[i];
  }
  __syncthreads();

  const int w = tid >> 6, l = tid & 63, c = l & 15, g = l >> 4;
  const int Ra = unit * 128 + w * 32;
  if (Ra >= M) return;                   // M is a multiple of 16; tile0 fully valid
  const bool vb = (Ra + 32) <= M;        // tile1 validity

  const short* wl = (const short*)smem + l * 8;   // lane's fragment base
  short* stg = (short*)(smem + 131072 + w * STG_B);

  const float* bias = (const float*)(wsc + WS_BIAS_OFF);
  float b1v[8], b2v[8], b3v[8];
#pragma unroll
  for (int ct = 0; ct < 8; ++ct) {
    b1v[ct] = bias[16 * ct + c];
    b2v[ct] = bias[128 + 16 * ct + c];
    b3v[ct] = bias[256 + 16 * ct + c];
  }

  f32x4 st[2][8], ot[2][8], xe[2][8], xa[2][4][2];

  // ---- prologue: t=0 loads; init state=out=x[0]
  {
    const float* E0 = X + (size_t)(Ra + 4 * g) * 128 + c;
    const float* A0 = X + (size_t)(Ra + c) * 128 + g * 8;
#pragma unroll
    for (int ct = 0; ct < 8; ++ct)
#pragma unroll
      for (int ri = 0; ri < 4; ++ri)
        xe[0][ct][ri] = E0[(size_t)ri * 128 + 16 * ct];
#pragma unroll
    for (int kc = 0; kc < 4; ++kc) {
      xa[0][kc][0] = *(const f32x4*)(A0 + kc * 32);
      xa[0][kc][1] = *(const f32x4*)(A0 + kc * 32 + 4);
    }
    if (vb) {
      const float* E1 = E0 + 16 * 128;
      const float* A1 = A0 + 16 * 128;
#pragma unroll
      for (int ct = 0; ct < 8; ++ct)
#pragma unroll
        for (int ri = 0; ri < 4; ++ri)
          xe[1][ct][ri] = E1[(size_t)ri * 128 + 16 * ct];
#pragma unroll
      for (int kc = 0; kc < 4; ++kc) {
        xa[1][kc][0] = *(const f32x4*)(A1 + kc * 32);
        xa[1][kc][1] = *(const f32x4*)(A1 + kc * 32 + 4);
      }
    } else {
#pragma unroll
      for (int ct = 0; ct < 8; ++ct)
#pragma unroll
        for (int ri = 0; ri < 4; ++ri) xe[1][ct][ri] = 0.f;
#pragma unroll
      for (int kc = 0; kc < 4; ++kc) {
        xa[1][kc][0] = (f32x4){0.f, 0.f, 0.f, 0.f};
        xa[1][kc][1] = (f32x4){0.f, 0.f, 0.f, 0.f};
      }
    }
#pragma unroll
    for (int rt = 0; rt < 2; ++rt)
#pragma unroll
      for (int ct = 0; ct < 8; ++ct) { st[rt][ct] = xe[rt][ct]; ot[rt][ct] = xe[rt][ct]; }
  }

#pragma unroll 1
  for (int t = 0; t < 8; ++t) {
    // 1. convert prefetched x to bf16 A-frags
    bf16x8 xf[2][4];
#pragma unroll
    for (int rt = 0; rt < 2; ++rt)
#pragma unroll
      for (int kc = 0; kc < 4; ++kc) {
        bf16x8 v;
#pragma unroll
        for (int j = 0; j < 4; ++j) {
          v[j]     = f2bf(xa[rt][kc][0][j]);
          v[4 + j] = f2bf(xa[rt][kc][1][j]);
        }
        xf[rt][kc] = v;
      }

    // 2. stage out -> LDS (16 rows at a time, wave-local), read A-frags back
    bf16x8 of[2][4];
#pragma unroll
    for (int rt = 0; rt < 2; ++rt) {
#pragma unroll
      for (int ct = 0; ct < 8; ++ct)
#pragma unroll
        for (int ri = 0; ri < 4; ++ri)
          stg[(4 * g + ri) * KPS + 16 * ct + c] = f2bf(ot[rt][ct][ri]);
#pragma unroll
      for (int kc = 0; kc < 4; ++kc)
        of[rt][kc] = *(const bf16x8*)(stg + c * KPS + kc * 32 + g * 8);
    }

    // 3. W1a (out) + W1b (x) + W2 (x): fragment-ordered, conflict-free LDS reads
    f32x4 accA[2][8], accB[2][8];
#pragma unroll
    for (int ct = 0; ct < 8; ++ct) {
      accA[0][ct] = (f32x4){0.f, 0.f, 0.f, 0.f};
      accA[1][ct] = (f32x4){0.f, 0.f, 0.f, 0.f};
      accB[0][ct] = (f32x4){0.f, 0.f, 0.f, 0.f};
      accB[1][ct] = (f32x4){0.f, 0.f, 0.f, 0.f};
#pragma unroll
      for (int kc = 0; kc < 4; ++kc) {
        bf16x8 w1a = *(const bf16x8*)(wl + 0 * WS_MAT_SH + (ct * 4 + kc) * 512);
        bf16x8 w1b = *(const bf16x8*)(wl + 1 * WS_MAT_SH + (ct * 4 + kc) * 512);
        bf16x8 w2  = *(const bf16x8*)(wl + 2 * WS_MAT_SH + (ct * 4 + kc) * 512);
        accA[0][ct] = __builtin_amdgcn_mfma_f32_16x16x32_bf16(of[0][kc], w1a, accA[0][ct], 0, 0, 0);
        accA[1][ct] = __builtin_amdgcn_mfma_f32_16x16x32_bf16(of[1][kc], w1a, accA[1][ct], 0, 0, 0);
        accA[0][ct] = __builtin_amdgcn_mfma_f32_16x16x32_bf16(xf[0][kc], w1b, accA[0][ct], 0, 0, 0);
        accA[1][ct] = __builtin_amdgcn_mfma_f32_16x16x32_bf16(xf[1][kc], w1b, accA[1][ct], 0, 0, 0);
        accB[0][ct] = __builtin_amdgcn_mfma_f32_16x16x32_bf16(xf[0][kc], w2, accB[0][ct], 0, 0, 0);
        accB[1][ct] = __builtin_amdgcn_mfma_f32_16x16x32_bf16(xf[1][kc], w2, accB[1][ct], 0, 0, 0);
      }
    }

    // 4. ew1: state update (f32 x from global, prefetched)
#pragma unroll
    for (int rt = 0; rt < 2; ++rt)
#pragma unroll
      for (int ct = 0; ct < 8; ++ct)
#pragma unroll
        for (int ri = 0; ri < 4; ++ri) {
          float f  = sigm(accA[rt][ct][ri] + b1v[ct]);
          float s2 = sigm(accB[rt][ct][ri] + b2v[ct]);
          st[rt][ct][ri] = st[rt][ct][ri] * f + s2 * tanh_(xe[rt][ct][ri]);
        }

    // 5. prefetch elementwise x for t+1 (dword loads; L1/L2-hot by step t+1's use)
    if (t < 7) {
      const float* En = X + (size_t)(t + 1) * M * 128 + (size_t)(Ra + 4 * g) * 128 + c;
#pragma unroll
      for (int ct = 0; ct < 8; ++ct)
#pragma unroll
        for (int ri = 0; ri < 4; ++ri)
          xe[0][ct][ri] = En[(size_t)ri * 128 + 16 * ct];
      if (vb) {
        const float* En1 = En + 16 * 128;
#pragma unroll
        for (int ct = 0; ct < 8; ++ct)
#pragma unroll
          for (int ri = 0; ri < 4; ++ri)
            xe[1][ct][ri] = En1[(size_t)ri * 128 + 16 * ct];
      }
    }

    // 6. W3 (accC reuses accA registers)
#pragma unroll
    for (int ct = 0; ct < 8; ++ct) {
      accA[0][ct] = (f32x4){0.f, 0.f, 0.f, 0.f};
      accA[1][ct] = (f32x4){0.f, 0.f, 0.f, 0.f};
#pragma unroll
      for (int kc = 0; kc < 4; ++kc) {
        bf16x8 w3 = *(const bf16x8*)(wl + 3 * WS_MAT_SH + (ct * 4 + kc) * 512);
        accA[0][ct] = __builtin_amdgcn_mfma_f32_16x16x32_bf16(xf[0][kc], w3, accA[0][ct], 0, 0, 0);
        accA[1][ct] = __builtin_amdgcn_mfma_f32_16x16x32_bf16(xf[1][kc], w3, accA[1][ct], 0, 0, 0);
      }
    }

    // 7. ew2: out
#pragma unroll
    for (int rt = 0; rt < 2; ++rt)
#pragma unroll
      for (int ct = 0; ct < 8; ++ct)
#pragma unroll
        for (int ri = 0; ri < 4; ++ri)
          ot[rt][ct][ri] = tanh_(st[rt][ct][ri]) * sigm(accA[rt][ct][ri] + b3v[ct]);

    // 8. prefetch x A-frag f32 for t+1 (converted at start of t+1)
    if (t < 7) {
      const float* An = X + (size_t)(t + 1) * M * 128 + (size_t)(Ra + c) * 128 + g * 8;
#pragma unroll
      for (int kc = 0; kc < 4; ++kc) {
        xa[0][kc][0] = *(const f32x4*)(An + kc * 32);
        xa[0][kc][1] = *(const f32x4*)(An + kc * 32 + 4);
      }
      if (vb) {
        const float* An1 = An + 16 * 128;
#pragma unroll
        for (int kc = 0; kc < 4; ++kc) {
          xa[1][kc][0] = *(const f32x4*)(An1 + kc * 32);
          xa[1][kc][1] = *(const f32x4*)(An1 + kc * 32 + 4);
        }
      }
    }
  }

  // ---- epilogue: store state & out (f32)
#pragma unroll
  for (int rt = 0; rt < 2; ++rt) {
    if (rt == 1 && !vb) break;
    float* Sp = S + (size_t)(Ra + 16 * rt + 4 * g) * 128 + c;
    float* Op = O + (size_t)(Ra + 16 * rt + 4 * g) * 128 + c;
#pragma unroll
    for (int ct = 0; ct < 8; ++ct)
#pragma unroll
      for (int ri = 0; ri < 4; ++ri) {
        Sp[(size_t)ri * 128 + 16 * ct] = st[rt][ct][ri];
        Op[(size_t)ri * 128 + 16 * ct] = ot[rt][ct][ri];
      }
  }
}

extern "C" void kernel_launch(void* const* d_in, const int* in_sizes, int n_in,
                              void* d_out, int out_size, void* d_ws, size_t ws_size,
                              hipStream_t stream) {
  (void)in_sizes; (void)n_in; (void)out_size; (void)ws_size;
  const float* xs = (const float*)d_in[0];
  const float* es = (const float*)d_in[1];
  const float* gs = (const float*)d_in[2];
  unsigned char* ws = (unsigned char*)d_ws;

  for (int comp = 0; comp < 3; ++comp) {
    const float* W1 = (const float*)d_in[3 + comp * 6 + 0];
    const float* b1 = (const float*)d_in[3 + comp * 6 + 1];
    const float* W2 = (const float*)d_in[3 + comp * 6 + 2];
    const float* b2 = (const float*)d_in[3 + comp * 6 + 3];
    const float* W3 = (const float*)d_in[3 + comp * 6 + 4];
    const float* b3 = (const float*)d_in[3 + comp * 6 + 5];
    prep_weights<<<4, 256, 0, stream>>>(W1, b1, W2, b2, W3, b3,
                                        ws + (size_t)comp * WS_COMP);
  }
  glstm<<<NBLOCKS, 256, 0, stream>>>(xs, es, gs, ws, (float*)d_out);
}

// Round 3
// 392.966 us; speedup vs baseline: 2.4825x; 2.4825x over previous
//
#include <hip/hip_runtime.h>

typedef __attribute__((ext_vector_type(8))) short bf16x8;   // MFMA A/B frag
typedef __attribute__((ext_vector_type(4))) float f32x4;    // MFMA C/D frag
typedef __attribute__((ext_vector_type(4))) short s16x4;    // 4 bf16 (8 B)

__device__ __forceinline__ short f2bf(float f) {
  unsigned u = __float_as_uint(f);
  u += 0x7fffu + ((u >> 16) & 1u);          // round-to-nearest-even
  return (short)(u >> 16);
}
__device__ __forceinline__ float bf2f(short s) {
  return __uint_as_float(((unsigned)(unsigned short)s) << 16);
}
__device__ __forceinline__ float sigm(float z) {
  return __builtin_amdgcn_rcpf(1.f + __builtin_amdgcn_exp2f(-1.44269504089f * z));
}
__device__ __forceinline__ float tanh_(float z) {
  return 1.f - 2.f * __builtin_amdgcn_rcpf(1.f + __builtin_amdgcn_exp2f(2.88539008178f * z));
}

// ---------- geometry ----------
// ws per component: 4 matrices as A-operand fragments (W^T strips), bf16.
//   mat m in {W1a(out),W1b(x),W2,W3}: frag (w,kc,lane) 16 B at ((w*4+kc)*64+l)*16
//   lane l holds A[wcol=16w+(l&15)][k=32kc+8*(l>>4)+j] = W[k(+rowoff)][wcol]
#define WS_MAT 32768
#define WS_COMP 131072
#define NODE_BLOCKS 1563
#define EDGE_BLOCKS 3125
#define GLOB_BLOCKS 16
#define NBLOCKS (NODE_BLOCKS + EDGE_BLOCKS + GLOB_BLOCKS)   // 4704

// swizzled byte offset within a [32 rows][256 B] LDS tile
__device__ __forceinline__ int swzb(int row, int byte) {
  return row * 256 + (byte ^ ((row & 7) << 4));
}

__global__ __launch_bounds__(256) void prep_weights(
    const float* __restrict__ W1, const float* __restrict__ W2,
    const float* __restrict__ W3, unsigned char* __restrict__ wsc) {
  const int m = blockIdx.x;   // 0=W1a 1=W1b 2=W2 3=W3
  const float* src; int rowoff = 0;
  if (m == 0)      { src = W1; }
  else if (m == 1) { src = W1; rowoff = 128; }
  else if (m == 2) { src = W2; }
  else             { src = W3; }
  short* dst = (short*)(wsc + (size_t)m * WS_MAT);
  for (int fi = threadIdx.x; fi < 2048; fi += 256) {
    int w = fi >> 8, kc = (fi >> 6) & 3, lane = fi & 63;
    int cc = lane & 15, gg = lane >> 4;
    int wcol = 16 * w + cc;
    int kb = 32 * kc + 8 * gg + rowoff;
    bf16x8 v;
#pragma unroll
    for (int j = 0; j < 8; ++j) v[j] = f2bf(src[(size_t)(kb + j) * 128 + wcol]);
    *(bf16x8*)(dst + (size_t)fi * 8) = v;
  }
}

__global__ __launch_bounds__(512, 2) void glstm(
    const float* __restrict__ xs, const float* __restrict__ es,
    const float* __restrict__ gs, const unsigned char* __restrict__ ws,
    const float* __restrict__ b1n, const float* __restrict__ b2n, const float* __restrict__ b3n,
    const float* __restrict__ b1e, const float* __restrict__ b2e, const float* __restrict__ b3e,
    const float* __restrict__ b1g, const float* __restrict__ b2g, const float* __restrict__ b3g,
    float* __restrict__ dout) {
  // LDS: x dbuf 2x8 KB + out dbuf 2x8 KB = 32 KB
  __shared__ __align__(16) unsigned char smem[32768];

  const int bid = blockIdx.x, tid = threadIdx.x;
  const float* X; const float *B1, *B2, *B3; float *S, *O; int M, unit, comp;
  if (bid < NODE_BLOCKS) {
    X = xs; M = 50000;  S = dout;              O = dout + 19265536L;
    unit = bid; comp = 0; B1 = b1n; B2 = b2n; B3 = b3n;
  } else if (bid < NODE_BLOCKS + EDGE_BLOCKS) {
    X = es; M = 100000; S = dout + 6400000L;   O = dout + 25665536L;
    unit = bid - NODE_BLOCKS; comp = 1; B1 = b1e; B2 = b2e; B3 = b3e;
  } else {
    X = gs; M = 512;    S = dout + 19200000L;  O = dout + 38465536L;
    unit = bid - (NODE_BLOCKS + EDGE_BLOCKS); comp = 2; B1 = b1g; B2 = b2g; B3 = b3g;
  }

  const int w = tid >> 6, l = tid & 63, c = l & 15, g = l >> 4;
  const int Ra = unit * 32;
  const bool v1 = (Ra + 16) < M;        // second 16-row tile valid (M % 16 == 0)

  // weights -> registers (once; reused across all rows and steps)
  bf16x8 wA[4][4];
  {
    const short* wsrc = (const short*)(ws + (size_t)comp * WS_COMP);
#pragma unroll
    for (int m = 0; m < 4; ++m)
#pragma unroll
      for (int kc = 0; kc < 4; ++kc)
        wA[m][kc] = *(const bf16x8*)(wsrc + (size_t)m * 16384 + ((w * 4 + kc) * 64 + l) * 8);
  }
  // biases for this wave's 4 output cols per lane (wcol = 16w+4g+ri)
  const f32x4 b1v = *(const f32x4*)(B1 + 16 * w + 4 * g);
  const f32x4 b2v = *(const f32x4*)(B2 + 16 * w + 4 * g);
  const f32x4 b3v = *(const f32x4*)(B3 + 16 * w + 4 * g);

  const int srow = tid >> 4, scol = (tid & 15) * 8;   // staging: row, f32-col
  // ---- stage x(0) -> xbuf0
  if (Ra + srow < M) {
    const float* p = X + (size_t)(Ra + srow) * 128 + scol;
    f32x4 a = *(const f32x4*)p, b = *(const f32x4*)(p + 4);
    bf16x8 vv;
#pragma unroll
    for (int j = 0; j < 4; ++j) { vv[j] = f2bf(a[j]); vv[4 + j] = f2bf(b[j]); }
    *(bf16x8*)((char*)smem + swzb(srow, scol * 2)) = vv;
  }
  __syncthreads();

  // init state = out = x[0] (bf16-rounded, matching what the MFMA path sees)
  f32x4 st0, st1, ot0, ot1;
  {
    s16x4 e0 = *(const s16x4*)((char*)smem + swzb(c, (16 * w + 4 * g) * 2));
#pragma unroll
    for (int ri = 0; ri < 4; ++ri) st0[ri] = bf2f(e0[ri]);
    if (v1) {
      s16x4 e1 = *(const s16x4*)((char*)smem + swzb(16 + c, (16 * w + 4 * g) * 2));
#pragma unroll
      for (int ri = 0; ri < 4; ++ri) st1[ri] = bf2f(e1[ri]);
    }
    ot0 = st0; ot1 = st1;
  }

#pragma unroll 1
  for (int t = 0; t < 8; ++t) {
    const int cur = t & 1;
    char* xbc = (char*)smem + cur * 8192;
    char* obc = (char*)smem + 16384 + cur * 8192;
    char* xbn = (char*)smem + (cur ^ 1) * 8192;
    char* obn = (char*)smem + 16384 + (cur ^ 1) * 8192;

    // issue x(t+1) prefetch early (completes under the MFMAs)
    f32x4 pa, pb; bool pf = false;
    if (t < 7 && (Ra + srow < M)) {
      const float* p = X + ((size_t)(t + 1) * M + Ra + srow) * 128 + scol;
      pa = *(const f32x4*)p; pb = *(const f32x4*)(p + 4);
      pf = true;
    }

#pragma unroll
    for (int ct = 0; ct < 2; ++ct) {
      if (ct == 0 || v1) {
        const int row = 16 * ct + c;
        bf16x8 xf[4], of[4];
#pragma unroll
        for (int kc = 0; kc < 4; ++kc)
          xf[kc] = *(const bf16x8*)(xbc + swzb(row, (32 * kc + 8 * g) * 2));
        if (t == 0) {
#pragma unroll
          for (int kc = 0; kc < 4; ++kc) of[kc] = xf[kc];   // out(-1) = x[0]
        } else {
#pragma unroll
          for (int kc = 0; kc < 4; ++kc)
            of[kc] = *(const bf16x8*)(obc + swzb(row, (32 * kc + 8 * g) * 2));
        }
        s16x4 xe4 = *(const s16x4*)(xbc + swzb(row, (16 * w + 4 * g) * 2));

        f32x4 aA = {0.f, 0.f, 0.f, 0.f}, aB = {0.f, 0.f, 0.f, 0.f}, aC = {0.f, 0.f, 0.f, 0.f};
#pragma unroll
        for (int kc = 0; kc < 4; ++kc) {
          aA = __builtin_amdgcn_mfma_f32_16x16x32_bf16(wA[0][kc], of[kc], aA, 0, 0, 0);
          aA = __builtin_amdgcn_mfma_f32_16x16x32_bf16(wA[1][kc], xf[kc], aA, 0, 0, 0);
          aB = __builtin_amdgcn_mfma_f32_16x16x32_bf16(wA[2][kc], xf[kc], aB, 0, 0, 0);
          aC = __builtin_amdgcn_mfma_f32_16x16x32_bf16(wA[3][kc], xf[kc], aC, 0, 0, 0);
        }

        s16x4 ob4;
#pragma unroll
        for (int ri = 0; ri < 4; ++ri) {
          float fgt = sigm(aA[ri] + b1v[ri]);
          float s2  = sigm(aB[ri] + b2v[ri]);
          float xev = bf2f(xe4[ri]);
          float sv  = (ct ? st1[ri] : st0[ri]) * fgt + s2 * tanh_(xev);
          float ov  = tanh_(sv) * sigm(aC[ri] + b3v[ri]);
          if (ct) { st1[ri] = sv; ot1[ri] = ov; } else { st0[ri] = sv; ot0[ri] = ov; }
          ob4[ri] = f2bf(ov);
        }
        *(s16x4*)(obn + swzb(row, (16 * w + 4 * g) * 2)) = ob4;
      }
    }

    // write staged x(t+1)
    if (pf) {
      bf16x8 vv;
#pragma unroll
      for (int j = 0; j < 4; ++j) { vv[j] = f2bf(pa[j]); vv[4 + j] = f2bf(pb[j]); }
      *(bf16x8*)(xbn + swzb(srow, scol * 2)) = vv;
    }
    __syncthreads();
  }

  // ---- epilogue: store state & out (f32), cols 16w+4g..+3 of rows 16ct+c
  {
    size_t o0 = (size_t)(Ra + c) * 128 + 16 * w + 4 * g;
    *(f32x4*)(S + o0) = st0;
    *(f32x4*)(O + o0) = ot0;
    if (v1) {
      size_t o1 = o0 + 16 * 128;
      *(f32x4*)(S + o1) = st1;
      *(f32x4*)(O + o1) = ot1;
    }
  }
}

extern "C" void kernel_launch(void* const* d_in, const int* in_sizes, int n_in,
                              void* d_out, int out_size, void* d_ws, size_t ws_size,
                              hipStream_t stream) {
  (void)in_sizes; (void)n_in; (void)out_size; (void)ws_size;
  const float* xs = (const float*)d_in[0];
  const float* es = (const float*)d_in[1];
  const float* gs = (const float*)d_in[2];
  unsigned char* ws = (unsigned char*)d_ws;

  for (int comp = 0; comp < 3; ++comp) {
    const float* W1 = (const float*)d_in[3 + comp * 6 + 0];
    const float* W2 = (const float*)d_in[3 + comp * 6 + 2];
    const float* W3 = (const float*)d_in[3 + comp * 6 + 4];
    prep_weights<<<4, 256, 0, stream>>>(W1, W2, W3, ws + (size_t)comp * WS_COMP);
  }
  glstm<<<NBLOCKS, 512, 0, stream>>>(
      xs, es, gs, ws,
      (const float*)d_in[4],  (const float*)d_in[6],  (const float*)d_in[8],
      (const float*)d_in[10], (const float*)d_in[12], (const float*)d_in[14],
      (const float*)d_in[16], (const float*)d_in[18], (const float*)d_in[20],
      (float*)d_out);
}

// Round 4
// 348.052 us; speedup vs baseline: 2.8029x; 1.1290x over previous
//
#include <hip/hip_runtime.h>

typedef __attribute__((ext_vector_type(8))) short bf16x8;   // MFMA A/B frag
typedef __attribute__((ext_vector_type(4))) float f32x4;    // MFMA C/D frag
typedef __attribute__((ext_vector_type(4))) short s16x4;    // 4 bf16 (8 B)

__device__ __forceinline__ unsigned cvt_pk(float lo, float hi) {
  unsigned r;
  asm("v_cvt_pk_bf16_f32 %0, %1, %2" : "=v"(r) : "v"(lo), "v"(hi));
  return r;
}
__device__ __forceinline__ float bf2f(short s) {
  return __uint_as_float(((unsigned)(unsigned short)s) << 16);
}
__device__ __forceinline__ float sigm(float z) {
  return __builtin_amdgcn_rcpf(1.f + __builtin_amdgcn_exp2f(-1.44269504089f * z));
}
__device__ __forceinline__ float tanh_(float z) {
  return 1.f - 2.f * __builtin_amdgcn_rcpf(1.f + __builtin_amdgcn_exp2f(2.88539008178f * z));
}

// ---------- geometry ----------
// ws per component: 4 matrices as A-operand fragments (W^T strips), bf16.
//   mat m in {W1a(out),W1b(x),W2,W3}: frag (w,kc,lane) 16 B at ((w*4+kc)*64+l)*16
#define WS_MAT 32768
#define WS_COMP 131072
#define NODE_BLOCKS 1563
#define EDGE_BLOCKS 3125
#define GLOB_BLOCKS 16
#define NBLOCKS (NODE_BLOCKS + EDGE_BLOCKS + GLOB_BLOCKS)   // 4704

// swizzled byte offset within a [32 rows][256 B] LDS tile
#define SWZ(row, byte) ((row) * 256 + ((byte) ^ (((row) & 7) << 4)))

__global__ __launch_bounds__(256) void prep_weights(
    const float* __restrict__ W1, const float* __restrict__ W2,
    const float* __restrict__ W3, unsigned char* __restrict__ wsc) {
  const int m = blockIdx.x;   // 0=W1a 1=W1b 2=W2 3=W3
  const float* src; int rowoff = 0;
  if (m == 0)      { src = W1; }
  else if (m == 1) { src = W1; rowoff = 128; }
  else if (m == 2) { src = W2; }
  else             { src = W3; }
  short* dst = (short*)(wsc + (size_t)m * WS_MAT);
  for (int fi = threadIdx.x; fi < 2048; fi += 256) {
    int w = fi >> 8, kc = (fi >> 6) & 3, lane = fi & 63;
    int cc = lane & 15, gg = lane >> 4;
    int wcol = 16 * w + cc;
    int kb = 32 * kc + 8 * gg + rowoff;
    union { bf16x8 h; unsigned u[4]; } v;
#pragma unroll
    for (int j = 0; j < 4; ++j)
      v.u[j] = cvt_pk(src[(size_t)(kb + 2 * j) * 128 + wcol],
                      src[(size_t)(kb + 2 * j + 1) * 128 + wcol]);
    *(bf16x8*)(dst + (size_t)fi * 8) = v.h;
  }
}

// x-only precompute for one 16-row tile (produces u, g3, aAx for the NEXT step)
__device__ __forceinline__ void pre_tile(
    const char* xb, int row, int g, int w,
    const bf16x8* w1b, const bf16x8* w2, const bf16x8* w3,
    f32x4 b1v, f32x4 b2v, f32x4 b3v,
    f32x4& u, f32x4& g3, f32x4& aAx) {
  bf16x8 xf[4];
#pragma unroll
  for (int kc = 0; kc < 4; ++kc)
    xf[kc] = *(const bf16x8*)(xb + SWZ(row, 64 * kc + 16 * g));
  s16x4 xe4 = *(const s16x4*)(xb + SWZ(row, 32 * w + 8 * g));
  f32x4 aB = b2v, aC = b3v, aX = b1v;
#pragma unroll
  for (int kc = 0; kc < 4; ++kc) {
    aX = __builtin_amdgcn_mfma_f32_16x16x32_bf16(w1b[kc], xf[kc], aX, 0, 0, 0);
    aB = __builtin_amdgcn_mfma_f32_16x16x32_bf16(w2[kc],  xf[kc], aB, 0, 0, 0);
    aC = __builtin_amdgcn_mfma_f32_16x16x32_bf16(w3[kc],  xf[kc], aC, 0, 0, 0);
  }
#pragma unroll
  for (int ri = 0; ri < 4; ++ri) {
    u[ri]  = sigm(aB[ri]) * tanh_(bf2f(xe4[ri]));
    g3[ri] = sigm(aC[ri]);
  }
  aAx = aX;
}

// serial (recurrent) part for one 16-row tile
__device__ __forceinline__ void ser_tile(
    const char* ofsrc, char* obw, int row, int g, int w,
    const bf16x8* w1a, f32x4 aAx, f32x4 u, f32x4 g3,
    f32x4& st, f32x4& ov) {
  bf16x8 of[4];
#pragma unroll
  for (int kc = 0; kc < 4; ++kc)
    of[kc] = *(const bf16x8*)(ofsrc + SWZ(row, 64 * kc + 16 * g));
  f32x4 aA = aAx;   // = x@W1b + b1 (precomputed)
#pragma unroll
  for (int kc = 0; kc < 4; ++kc)
    aA = __builtin_amdgcn_mfma_f32_16x16x32_bf16(w1a[kc], of[kc], aA, 0, 0, 0);
#pragma unroll
  for (int ri = 0; ri < 4; ++ri) {
    float fgt = sigm(aA[ri]);
    st[ri] = st[ri] * fgt + u[ri];
    ov[ri] = tanh_(st[ri]) * g3[ri];
  }
  union { s16x4 v; unsigned uu[2]; } ob;
  ob.uu[0] = cvt_pk(ov[0], ov[1]);
  ob.uu[1] = cvt_pk(ov[2], ov[3]);
  *(s16x4*)(obw + SWZ(row, 32 * w + 8 * g)) = ob.v;
}

__global__ __launch_bounds__(512, 2) void glstm(
    const float* __restrict__ xs, const float* __restrict__ es,
    const float* __restrict__ gs, const unsigned char* __restrict__ ws,
    const float* __restrict__ b1n, const float* __restrict__ b2n, const float* __restrict__ b3n,
    const float* __restrict__ b1e, const float* __restrict__ b2e, const float* __restrict__ b3e,
    const float* __restrict__ b1g, const float* __restrict__ b2g, const float* __restrict__ b3g,
    float* __restrict__ dout) {
  // LDS: 3 x-buffers (8 KB) + 2 out-buffers (8 KB) = 40 KB
  __shared__ __align__(16) unsigned char smem[40960];

  const int bid = blockIdx.x, tid = threadIdx.x;
  const float* X; const float *B1, *B2, *B3; float *S, *O; int M, unit, comp;
  if (bid < NODE_BLOCKS) {
    X = xs; M = 50000;  S = dout;              O = dout + 19265536L;
    unit = bid; comp = 0; B1 = b1n; B2 = b2n; B3 = b3n;
  } else if (bid < NODE_BLOCKS + EDGE_BLOCKS) {
    X = es; M = 100000; S = dout + 6400000L;   O = dout + 25665536L;
    unit = bid - NODE_BLOCKS; comp = 1; B1 = b1e; B2 = b2e; B3 = b3e;
  } else {
    X = gs; M = 512;    S = dout + 19200000L;  O = dout + 38465536L;
    unit = bid - (NODE_BLOCKS + EDGE_BLOCKS); comp = 2; B1 = b1g; B2 = b2g; B3 = b3g;
  }

  const int w = tid >> 6, l = tid & 63, c = l & 15, g = l >> 4;
  const int Ra = unit * 32;
  const bool v1 = (Ra + 16) < M;          // tile1 validity (M % 16 == 0)
  const int row0 = c, row1 = 16 + c;

  // weights -> registers (once)
  bf16x8 wA[4][4];
  {
    const short* wsrc = (const short*)(ws + (size_t)comp * WS_COMP);
#pragma unroll
    for (int m = 0; m < 4; ++m)
#pragma unroll
      for (int kc = 0; kc < 4; ++kc)
        wA[m][kc] = *(const bf16x8*)(wsrc + (size_t)m * 16384 + ((w * 4 + kc) * 64 + l) * 8);
  }
  const f32x4 b1v = *(const f32x4*)(B1 + 16 * w + 4 * g);
  const f32x4 b2v = *(const f32x4*)(B2 + 16 * w + 4 * g);
  const f32x4 b3v = *(const f32x4*)(B3 + 16 * w + 4 * g);

  char* xb0 = (char*)smem;
  char* xb1 = (char*)smem + 8192;
  char* xb2 = (char*)smem + 16384;
  char* ob0 = (char*)smem + 24576;
  char* ob1 = (char*)smem + 32768;

  const int srow = tid >> 4;
  const int sbyte = (tid & 15) * 16;      // bf16 byte col
  const int scol = (tid & 15) * 8;        // f32 col
  const bool sv = (Ra + srow) < M;

  // ---- prologue: stage x(0)->xb0, x(1)->xb1
  if (sv) {
    const float* p0 = X + (size_t)(Ra + srow) * 128 + scol;
    const float* p1 = p0 + (size_t)M * 128;
    f32x4 a0 = *(const f32x4*)p0, a1 = *(const f32x4*)(p0 + 4);
    f32x4 a2 = *(const f32x4*)p1, a3 = *(const f32x4*)(p1 + 4);
    union { bf16x8 h; unsigned u[4]; } o;
    o.u[0] = cvt_pk(a0[0], a0[1]); o.u[1] = cvt_pk(a0[2], a0[3]);
    o.u[2] = cvt_pk(a1[0], a1[1]); o.u[3] = cvt_pk(a1[2], a1[3]);
    *(bf16x8*)(xb0 + SWZ(srow, sbyte)) = o.h;
    o.u[0] = cvt_pk(a2[0], a2[1]); o.u[1] = cvt_pk(a2[2], a2[3]);
    o.u[2] = cvt_pk(a3[0], a3[1]); o.u[3] = cvt_pk(a3[2], a3[3]);
    *(bf16x8*)(xb1 + SWZ(srow, sbyte)) = o.h;
  }
  __syncthreads();

  // state init = x[0] (bf16-rounded); precompute step-0 x-terms from xb0
  f32x4 st0, st1, ot0, ot1;
  {
    s16x4 e0 = *(const s16x4*)(xb0 + SWZ(row0, 32 * w + 8 * g));
    s16x4 e1 = *(const s16x4*)(xb0 + SWZ(row1, 32 * w + 8 * g));
#pragma unroll
    for (int ri = 0; ri < 4; ++ri) { st0[ri] = bf2f(e0[ri]); st1[ri] = bf2f(e1[ri]); }
  }
  f32x4 u0, u1, g30, g31, aAx0, aAx1;
  pre_tile(xb0, row0, g, w, wA[1], wA[2], wA[3], b1v, b2v, b3v, u0, g30, aAx0);
  pre_tile(xb0, row1, g, w, wA[1], wA[2], wA[3], b1v, b2v, b3v, u1, g31, aAx1);

  // rotating buffers: xr holds x(t+1), xw = target for x(t+2), xsp spare (x(0) at t=0)
  char* xr = xb1; char* xw = xb2; char* xsp = xb0;
  char* orf = ob0; char* owf = ob1;

#pragma unroll 1
  for (int t = 0; t < 8; ++t) {
    // prefetch x(t+2) (issued early; written to LDS at step end)
    f32x4 pa, pb;
    const bool pf = (t < 6) && sv;
    if (pf) {
      const float* p = X + ((size_t)(t + 2) * M + Ra + srow) * 128 + scol;
      pa = *(const f32x4*)p; pb = *(const f32x4*)(p + 4);
    }

    // serial recurrent part (of = out(t-1); at t=0 out(-1)=x(0) in xsp)
    const char* ofs = (t == 0) ? (const char*)xsp : (const char*)orf;
    f32x4 ov0, ov1;
    ser_tile(ofs, owf, row0, g, w, wA[0], aAx0, u0, g30, st0, ov0);
    ser_tile(ofs, owf, row1, g, w, wA[0], aAx1, u1, g31, st1, ov1);
    if (t == 7) { ot0 = ov0; ot1 = ov1; }

    // precompute x-terms for step t+1 (independent of the serial chain)
    if (t < 7) {
      pre_tile(xr, row0, g, w, wA[1], wA[2], wA[3], b1v, b2v, b3v, u0, g30, aAx0);
      pre_tile(xr, row1, g, w, wA[1], wA[2], wA[3], b1v, b2v, b3v, u1, g31, aAx1);
    }

    // write staged x(t+2)
    if (pf) {
      union { bf16x8 h; unsigned u[4]; } o;
      o.u[0] = cvt_pk(pa[0], pa[1]); o.u[1] = cvt_pk(pa[2], pa[3]);
      o.u[2] = cvt_pk(pb[0], pb[1]); o.u[3] = cvt_pk(pb[2], pb[3]);
      *(bf16x8*)(xw + SWZ(srow, sbyte)) = o.h;
    }
    __syncthreads();

    // rotate buffers
    char* tx = xsp; xsp = xr; xr = xw; xw = tx;
    char* to = orf; orf = owf; owf = to;
  }

  // ---- epilogue: store state & out (f32)
  {
    size_t o0 = (size_t)(Ra + row0) * 128 + 16 * w + 4 * g;
    *(f32x4*)(S + o0) = st0;
    *(f32x4*)(O + o0) = ot0;
    if (v1) {
      size_t o1 = (size_t)(Ra + row1) * 128 + 16 * w + 4 * g;
      *(f32x4*)(S + o1) = st1;
      *(f32x4*)(O + o1) = ot1;
    }
  }
}

extern "C" void kernel_launch(void* const* d_in, const int* in_sizes, int n_in,
                              void* d_out, int out_size, void* d_ws, size_t ws_size,
                              hipStream_t stream) {
  (void)in_sizes; (void)n_in; (void)out_size; (void)ws_size;
  const float* xs = (const float*)d_in[0];
  const float* es = (const float*)d_in[1];
  const float* gs = (const float*)d_in[2];
  unsigned char* ws = (unsigned char*)d_ws;

  for (int comp = 0; comp < 3; ++comp) {
    const float* W1 = (const float*)d_in[3 + comp * 6 + 0];
    const float* W2 = (const float*)d_in[3 + comp * 6 + 2];
    const float* W3 = (const float*)d_in[3 + comp * 6 + 4];
    prep_weights<<<4, 256, 0, stream>>>(W1, W2, W3, ws + (size_t)comp * WS_COMP);
  }
  glstm<<<NBLOCKS, 512, 0, stream>>>(
      xs, es, gs, ws,
      (const float*)d_in[4],  (const float*)d_in[6],  (const float*)d_in[8],
      (const float*)d_in[10], (const float*)d_in[12], (const float*)d_in[14],
      (const float*)d_in[16], (const float*)d_in[18], (const float*)d_in[20],
      (float*)d_out);
}